// Round 8
// baseline (280.814 us; speedup 1.0000x reference)
//
#include <hip/hip_runtime.h>
#include <stdint.h>

// Problem constants
#define M_TOK   16384        // 8 * 2048 tokens
#define EMBED   1024
#define FFN     4096
#define NQ      10

#define GK 4096
#define GN 1024
#define BK 64
#define NT (GK / BK)         // 64 K-tiles

typedef __attribute__((ext_vector_type(8))) short  bf16x8;
typedef __attribute__((ext_vector_type(4))) float  f32x4;
typedef __attribute__((ext_vector_type(8))) unsigned short u16x8;

static __device__ __forceinline__ unsigned short f2bf(float f) {
    union { float f; unsigned u; } v; v.f = f;
    unsigned r = v.u + 0x7FFF + ((v.u >> 16) & 1);   // round-to-nearest-even
    return (unsigned short)(r >> 16);
}

// ---------------------------------------------------------------------------
// Kernel 0: w1cT[i][f] = w1[f][i] * cos(ry[i])   (transpose + premultiply)
// ---------------------------------------------------------------------------
__global__ __launch_bounds__(256) void prep_w1(
    const float* __restrict__ w1, const float* __restrict__ ry,
    float* __restrict__ w1cT)
{
    __shared__ float cry[16];
    if (threadIdx.x < NQ) cry[threadIdx.x] = cosf(ry[threadIdx.x]);
    __syncthreads();
    const int f = blockIdx.x * 256 + threadIdx.x;   // 0..4095
#pragma unroll
    for (int i = 0; i < NQ; ++i)
        w1cT[i * FFN + f] = w1[f * NQ + i] * cry[i];
}

// ---------------------------------------------------------------------------
// Kernel 1: h[t][f] = relu( sum_i cos(x[t][i]) * w1cT[i][f] ) -> bf16
// (frozen -- "rest" time is insensitive to this kernel's form)
// ---------------------------------------------------------------------------
__global__ __launch_bounds__(256) void compute_h(
    const float* __restrict__ x, const float* __restrict__ w1cT,
    unsigned short* __restrict__ h)
{
    __shared__ float cq[32 * 16];    // 2 KB, stride 16 for alignment

    const int tid = threadIdx.x;
    const int t0  = blockIdx.x * 32;
    const int fb  = blockIdx.y * 2048 + tid * 8;   // this thread's 8 f's

    for (int idx = tid; idx < 32 * NQ; idx += 256) {
        int t = idx / NQ;
        int i = idx - t * NQ;
        cq[t * 16 + i] = cosf(x[(size_t)(t0 + t) * EMBED + i]);
    }
    __syncthreads();

    float wf[8][NQ];
#pragma unroll
    for (int i = 0; i < NQ; ++i) {
        const float4 lo = *(const float4*)(w1cT + (size_t)i * FFN + fb);
        const float4 hi = *(const float4*)(w1cT + (size_t)i * FFN + fb + 4);
        wf[0][i] = lo.x; wf[1][i] = lo.y; wf[2][i] = lo.z; wf[3][i] = lo.w;
        wf[4][i] = hi.x; wf[5][i] = hi.y; wf[6][i] = hi.z; wf[7][i] = hi.w;
    }

    for (int t = 0; t < 32; ++t) {
        const float4 c0 = *(const float4*)&cq[t * 16 + 0];
        const float4 c1 = *(const float4*)&cq[t * 16 + 4];
        const float2 c2 = *(const float2*)&cq[t * 16 + 8];
        u16x8 v;
#pragma unroll
        for (int fi = 0; fi < 8; ++fi) {
            float s = c0.x * wf[fi][0] + c0.y * wf[fi][1] + c0.z * wf[fi][2]
                    + c0.w * wf[fi][3] + c1.x * wf[fi][4] + c1.y * wf[fi][5]
                    + c1.z * wf[fi][6] + c1.w * wf[fi][7] + c2.x * wf[fi][8]
                    + c2.y * wf[fi][9];
            v[fi] = f2bf(fmaxf(s, 0.f));
        }
        *(u16x8*)(h + (size_t)(t0 + t) * FFN + fb) = v;
    }
}

// ---------------------------------------------------------------------------
// Kernel 2: w2 fp32 -> bf16.  4,194,304 elems, 8 per thread.
// ---------------------------------------------------------------------------
__global__ __launch_bounds__(256) void conv_w2(
    const float* __restrict__ w2, unsigned short* __restrict__ o)
{
    const int idx = (blockIdx.x * 256 + threadIdx.x) * 8;
    float4 a = *(const float4*)(w2 + idx);
    float4 b = *(const float4*)(w2 + idx + 4);
    u16x8 v;
    v[0] = f2bf(a.x); v[1] = f2bf(a.y); v[2] = f2bf(a.z); v[3] = f2bf(a.w);
    v[4] = f2bf(b.x); v[5] = f2bf(b.y); v[6] = f2bf(b.z); v[7] = f2bf(b.w);
    *(u16x8*)(o + idx) = v;
}

// ---------------------------------------------------------------------------
// Kernel 3: C[M][N] = A[M][K] * B[N][K]^T   (bf16 in, fp32 out)
//
// 8-phase / 2-K-tile schedule with counted vmcnt (T2+T3+T4+T5), R7 fixed:
// fragment mapping now aligned to STAGE-HALF granularity so the per-phase
// vmcnt(4) ledger is consistent for ALL waves:
//   A fragment row = mh*128 + wm*64 + i*16 + rr   (half outer, wave inner)
//   B fragment row = nh*128 + wn*32 + j*16 + rr
// => a phase's reads touch exactly one 128-row stage half of A and one of B.
// (R7's bug: wm*128 + mh*64 made wm=1 waves read the OTHER stage half,
//  which vmcnt(4) had intentionally left in flight -> race, absmax 0.9.)
//
// Phase = {ds_read quadrant operands; stage ONE half-tile; s_barrier;
//          lgkmcnt(0)+sched_barrier; setprio(1) 16 MFMA setprio(0);
//          vmcnt(4); s_barrier}.
// Stage order: P1:vA0 P2:vB0 P3:vB1 P4:vA1 P5:u'A0 P6:u'B0 P7:u'B1 P8:u'A1.
// Retirement-before-consumption (half-granular, enumerated):
//   P5 reads A[0,128)=P1 (retired P3-end), B[0,128)=P2 (retired P4-end);
//   P6 reads B[128,256)=P3 (retired P5-end); P7 reads A[128,256)=P4
//   (retired P6-end); nP1 reads P5/P6 (retired P7/P8-end); nP2 reads P7
//   (retired nP1-end); nP3 reads P8 (retired nP2-end).  vmcnt NEVER 0 in
//   the loop; every stage has >=3 phases (~1200 cyc > ~900 HBM) of cover.
// Write-after-read: every stage lands >=2 barrier-phases after the target
// region's last ds_read completed (lgkmcnt(0)+barriers).  Tail: last iter
// P5-P8 stage ko=0 garbage into buf0 (never re-read), counts uniform.
// C output mapping (bijective): m = m0+(i>>2)*128+wm*64+(i&3)*16+rb+r,
//                               n = n0+(j>>1)*128+wn*32+(j&1)*16+cn.
// ---------------------------------------------------------------------------
#define GL2LDS(g, l) \
    __builtin_amdgcn_global_load_lds( \
        (const __attribute__((address_space(1))) void*)(g), \
        (__attribute__((address_space(3))) void*)(l), 16, 0, 0)

__global__ __launch_bounds__(512, 2) void gemm_bt(
    const unsigned short* __restrict__ A,
    const unsigned short* __restrict__ B,
    float* __restrict__ C)
{
    __shared__ __align__(16) unsigned short As[2][256 * BK];   // 2 x 32 KB
    __shared__ __align__(16) unsigned short Bs[2][256 * BK];   // 2 x 32 KB

    const int tid  = threadIdx.x;
    const int wv   = tid >> 6;         // 0..7
    const int lane = tid & 63;
    const int wm   = wv >> 2;          // 0..1  (M sub-block within each half)
    const int wn   = wv & 3;           // 0..3  (N sub-block within each half)

    const int bid = blockIdx.x;
    const int wg  = (bid & 7) * 32 + (bid >> 3);   // XCD-chunked remap
    const int m0  = (wg >> 2) * 256;               // 64 m-blocks
    const int n0  = (wg & 3) * 256;                // 4 n-blocks

    // staging: per half-tile (128 rows), wave covers 16 rows as 2 loads of
    // 8 rows; lane -> row lane>>3, chunk (lane&7)^(lane>>3) (XOR swizzle).
    const int srow8 = lane >> 3;
    const int schk  = (lane & 7) ^ srow8;
    const char* ag = (const char*)A +
        ((size_t)(m0 + wv * 16 + srow8) * GK + schk * 8) * 2;
    const char* bg = (const char*)B +
        ((size_t)(n0 + wv * 16 + srow8) * GK + schk * 8) * 2;
    const size_t ROW8 = (size_t)8 * GK * 2;     // 8 rows in global bytes
    const size_t HALF = (size_t)128 * GK * 2;   // 128 rows in global bytes

#define STAGE_A(buf, half, ko) do { \
    GL2LDS(ag + (ko) + (half) * HALF,        (char*)As[buf] + ((half) * 128 + wv * 16) * 128); \
    GL2LDS(ag + (ko) + (half) * HALF + ROW8, (char*)As[buf] + ((half) * 128 + wv * 16 + 8) * 128); \
} while (0)
#define STAGE_B(buf, half, ko) do { \
    GL2LDS(bg + (ko) + (half) * HALF,        (char*)Bs[buf] + ((half) * 128 + wv * 16) * 128); \
    GL2LDS(bg + (ko) + (half) * HALF + ROW8, (char*)Bs[buf] + ((half) * 128 + wv * 16 + 8) * 128); \
} while (0)

    // fragment read coordinates -- HALF-ALIGNED mapping (the R7 fix)
    const int rr  = lane & 15;
    const int fsw = lane & 7;
    const int cc  = lane >> 4;
#define CHOFF(s) ((((s) * 4 + cc) ^ fsw) * 16)
#define RD_A(dst, Pt, mh) do { \
    _Pragma("unroll") \
    for (int s_ = 0; s_ < 2; ++s_) \
        _Pragma("unroll") \
        for (int i_ = 0; i_ < 4; ++i_) \
            dst[s_][i_] = *(const bf16x8*)((Pt) + \
                ((mh) * 128 + wm * 64 + i_ * 16 + rr) * 128 + CHOFF(s_)); \
} while (0)
#define RD_B(dst, Pt, nh) do { \
    _Pragma("unroll") \
    for (int s_ = 0; s_ < 2; ++s_) \
        _Pragma("unroll") \
        for (int j_ = 0; j_ < 2; ++j_) \
            dst[s_][j_] = *(const bf16x8*)((Pt) + \
                ((nh) * 128 + wn * 32 + j_ * 16 + rr) * 128 + CHOFF(s_)); \
} while (0)

    f32x4 acc[8][4] = {};

#define MFMA16(AF, BF, I0, J0) do { \
    __builtin_amdgcn_s_setprio(1); \
    _Pragma("unroll") \
    for (int s_ = 0; s_ < 2; ++s_) \
        _Pragma("unroll") \
        for (int i_ = 0; i_ < 4; ++i_) \
            _Pragma("unroll") \
            for (int j_ = 0; j_ < 2; ++j_) \
                acc[(I0) + i_][(J0) + j_] = __builtin_amdgcn_mfma_f32_16x16x32_bf16( \
                    AF[s_][i_], BF[s_][j_], acc[(I0) + i_][(J0) + j_], 0, 0, 0); \
    __builtin_amdgcn_s_setprio(0); \
} while (0)

    // phase sync: enter-barrier + drain LDS reads, pin MFMA after
#define SYNC_IN do { \
    __builtin_amdgcn_s_barrier(); \
    asm volatile("s_waitcnt lgkmcnt(0)" ::: "memory"); \
    __builtin_amdgcn_sched_barrier(0); \
} while (0)
    // phase exit: counted vmcnt (2 half-tiles stay in flight) + barrier
#define SYNC_OUT do { \
    asm volatile("s_waitcnt vmcnt(4)" ::: "memory"); \
    __builtin_amdgcn_s_barrier(); \
} while (0)

    bf16x8 aF[2][4], b0[2][2], b1[2][2];

    // prologue: stage tile0 halves in consumption order {A0,B0,B1,A1};
    // vmcnt(4) leaves {B1,A1} flying -- identical to steady-state P8 exit.
    STAGE_A(0, 0, 0); STAGE_B(0, 0, 0);
    STAGE_B(0, 1, 0); STAGE_A(0, 1, 0);
    asm volatile("s_waitcnt vmcnt(4)" ::: "memory");
    __builtin_amdgcn_s_barrier();

    // one K-tile = 4 phases; SHx stages one half-tile into the other buf
#define TILE4(cur, SH1, SH2, SH3, SH4) do { \
    const char* At = (const char*)As[cur]; \
    const char* Bt = (const char*)Bs[cur]; \
    /* Pa: Q(mh0,nh0) -- reads A half0, B half0 */ \
    RD_A(aF, At, 0); RD_B(b0, Bt, 0); \
    SH1; \
    SYNC_IN; MFMA16(aF, b0, 0, 0); SYNC_OUT; \
    /* Pb: Q(mh0,nh1) -- reads B half1 */ \
    RD_B(b1, Bt, 1); \
    SH2; \
    SYNC_IN; MFMA16(aF, b1, 0, 2); SYNC_OUT; \
    /* Pc: Q(mh1,nh1) -- reads A half1 */ \
    RD_A(aF, At, 1); \
    SH3; \
    SYNC_IN; MFMA16(aF, b1, 4, 2); SYNC_OUT; \
    /* Pd: Q(mh1,nh0) -- no reads */ \
    SH4; \
    SYNC_IN; MFMA16(aF, b0, 4, 0); SYNC_OUT; \
} while (0)

#pragma unroll 1
    for (int tt = 0; tt < NT / 2; ++tt) {
        const size_t kv = (size_t)(2 * tt + 1) * 128;   // tile v (always real)
        const size_t ku = (2 * tt + 2 < NT) ? (size_t)(2 * tt + 2) * 128 : 0;
        // tile u = 2tt from buf0; stage v into buf1 (order A0,B0,B1,A1)
        TILE4(0, STAGE_A(1, 0, kv), STAGE_B(1, 0, kv),
                 STAGE_B(1, 1, kv), STAGE_A(1, 1, kv));
        // tile v = 2tt+1 from buf1; stage u' into buf0
        TILE4(1, STAGE_A(0, 0, ku), STAGE_B(0, 0, ku),
                 STAGE_B(0, 1, ku), STAGE_A(0, 1, ku));
    }

    // drain tail garbage stages before epilogue
    asm volatile("s_waitcnt vmcnt(0)" ::: "memory");

    // epilogue: per-MFMA C/D layout col = lane&15, row = (lane>>4)*4 + reg;
    // half-aligned block mapping (matches RD_A/RD_B rows)
    const int cn = lane & 15;
    const int rb = (lane >> 4) * 4;
#pragma unroll
    for (int i = 0; i < 8; ++i)
#pragma unroll
        for (int j = 0; j < 4; ++j)
#pragma unroll
            for (int r = 0; r < 4; ++r) {
                const int m = m0 + (i >> 2) * 128 + wm * 64 + (i & 3) * 16 + rb + r;
                const int n = n0 + (j >> 1) * 128 + wn * 32 + (j & 1) * 16 + cn;
                C[(size_t)m * GN + n] = acc[i][j][r];
            }
}

// ---------------------------------------------------------------------------
extern "C" void kernel_launch(void* const* d_in, const int* in_sizes, int n_in,
                              void* d_out, int out_size, void* d_ws, size_t ws_size,
                              hipStream_t stream) {
    const float* x  = (const float*)d_in[0];
    const float* ry = (const float*)d_in[1];
    const float* w1 = (const float*)d_in[2];
    const float* w2 = (const float*)d_in[3];
    float* out = (float*)d_out;

    unsigned short* h   = (unsigned short*)d_ws;                       // 128 MiB
    unsigned short* w2b = (unsigned short*)((char*)d_ws +
                           (size_t)M_TOK * FFN * sizeof(unsigned short));
    // w1cT (160 KB) overlays the w2b region: consumed before conv_w2 writes.
    float* w1cT = (float*)w2b;

    prep_w1<<<dim3(FFN / 256), 256, 0, stream>>>(w1, ry, w1cT);
    compute_h<<<dim3(512, 2), 256, 0, stream>>>(x, w1cT, h);
    conv_w2<<<dim3((EMBED * FFN) / (256 * 8)), 256, 0, stream>>>(w2, w2b);
    gemm_bt<<<dim3(256), 512, 0, stream>>>(h, w2b, out);
}

// Round 9
// 280.118 us; speedup vs baseline: 1.0025x; 1.0025x over previous
//
#include <hip/hip_runtime.h>
#include <stdint.h>

// Problem constants
#define M_TOK   16384        // 8 * 2048 tokens
#define EMBED   1024
#define FFN     4096
#define NQ      10

#define GK 4096
#define GN 1024
#define BK 64
#define NT (GK / BK)         // 64 K-tiles

typedef __attribute__((ext_vector_type(8))) short  bf16x8;
typedef __attribute__((ext_vector_type(4))) float  f32x4;
typedef __attribute__((ext_vector_type(8))) unsigned short u16x8;

static __device__ __forceinline__ unsigned short f2bf(float f) {
    union { float f; unsigned u; } v; v.f = f;
    unsigned r = v.u + 0x7FFF + ((v.u >> 16) & 1);   // round-to-nearest-even
    return (unsigned short)(r >> 16);
}

// ---------------------------------------------------------------------------
// Kernel 0: w1cT[i][f] = w1[f][i] * cos(ry[i])   (transpose + premultiply)
// ---------------------------------------------------------------------------
__global__ __launch_bounds__(256) void prep_w1(
    const float* __restrict__ w1, const float* __restrict__ ry,
    float* __restrict__ w1cT)
{
    __shared__ float cry[16];
    if (threadIdx.x < NQ) cry[threadIdx.x] = cosf(ry[threadIdx.x]);
    __syncthreads();
    const int f = blockIdx.x * 256 + threadIdx.x;   // 0..4095
#pragma unroll
    for (int i = 0; i < NQ; ++i)
        w1cT[i * FFN + f] = w1[f * NQ + i] * cry[i];
}

// ---------------------------------------------------------------------------
// Kernel 1: h[t][f] = relu( sum_i cos(x[t][i]) * w1cT[i][f] ) -> bf16
// (frozen -- "rest" time is insensitive to this kernel's form)
// ---------------------------------------------------------------------------
__global__ __launch_bounds__(256) void compute_h(
    const float* __restrict__ x, const float* __restrict__ w1cT,
    unsigned short* __restrict__ h)
{
    __shared__ float cq[32 * 16];    // 2 KB, stride 16 for alignment

    const int tid = threadIdx.x;
    const int t0  = blockIdx.x * 32;
    const int fb  = blockIdx.y * 2048 + tid * 8;   // this thread's 8 f's

    for (int idx = tid; idx < 32 * NQ; idx += 256) {
        int t = idx / NQ;
        int i = idx - t * NQ;
        cq[t * 16 + i] = cosf(x[(size_t)(t0 + t) * EMBED + i]);
    }
    __syncthreads();

    float wf[8][NQ];
#pragma unroll
    for (int i = 0; i < NQ; ++i) {
        const float4 lo = *(const float4*)(w1cT + (size_t)i * FFN + fb);
        const float4 hi = *(const float4*)(w1cT + (size_t)i * FFN + fb + 4);
        wf[0][i] = lo.x; wf[1][i] = lo.y; wf[2][i] = lo.z; wf[3][i] = lo.w;
        wf[4][i] = hi.x; wf[5][i] = hi.y; wf[6][i] = hi.z; wf[7][i] = hi.w;
    }

    for (int t = 0; t < 32; ++t) {
        const float4 c0 = *(const float4*)&cq[t * 16 + 0];
        const float4 c1 = *(const float4*)&cq[t * 16 + 4];
        const float2 c2 = *(const float2*)&cq[t * 16 + 8];
        u16x8 v;
#pragma unroll
        for (int fi = 0; fi < 8; ++fi) {
            float s = c0.x * wf[fi][0] + c0.y * wf[fi][1] + c0.z * wf[fi][2]
                    + c0.w * wf[fi][3] + c1.x * wf[fi][4] + c1.y * wf[fi][5]
                    + c1.z * wf[fi][6] + c1.w * wf[fi][7] + c2.x * wf[fi][8]
                    + c2.y * wf[fi][9];
            v[fi] = f2bf(fmaxf(s, 0.f));
        }
        *(u16x8*)(h + (size_t)(t0 + t) * FFN + fb) = v;
    }
}

// ---------------------------------------------------------------------------
// Kernel 2: w2 fp32 -> bf16.  4,194,304 elems, 8 per thread.
// ---------------------------------------------------------------------------
__global__ __launch_bounds__(256) void conv_w2(
    const float* __restrict__ w2, unsigned short* __restrict__ o)
{
    const int idx = (blockIdx.x * 256 + threadIdx.x) * 8;
    float4 a = *(const float4*)(w2 + idx);
    float4 b = *(const float4*)(w2 + idx + 4);
    u16x8 v;
    v[0] = f2bf(a.x); v[1] = f2bf(a.y); v[2] = f2bf(a.z); v[3] = f2bf(a.w);
    v[4] = f2bf(b.x); v[5] = f2bf(b.y); v[6] = f2bf(b.z); v[7] = f2bf(b.w);
    *(u16x8*)(o + idx) = v;
}

// ---------------------------------------------------------------------------
// Kernel 3: C[M][N] = A[M][K] * B[N][K]^T   (bf16 in, fp32 out)
//
// Exact m201 8-phase / 2-K-tile schedule: vmcnt(6) at P4/P8 ONLY (3
// half-tiles in flight, 5-phase stage->consume lead), lgkmcnt(8) throttle
// after 12-read phases, no sched_barrier. R8's verified half-aligned
// fragment mapping + XOR chunk swizzle + epilogue kept bit-for-bit.
//
// Iter tt: tile u=2tt (buf0, P1-P4), v=2tt+1 (buf1, P5-P8),
//          u'=2tt+2 (buf0), w=2tt+3 (buf1).
// Stage map: P1:vA1  P2:u'A0  P3:u'B0  P4:u'B1+vmcnt(6)
//            P5:u'A1 P6:wA0   P7:wB0   P8:wB1+vmcnt(6)
// Ledger (per wave, 2 loads/stage; enumerated):
//   entry flight = {vA0,vB0,vB1} (6, staged prev P6-P8).
//   P4's vmcnt(6): 14 outstanding -> retires prev-P6,P7,P8 + P1
//     => P5 reads vA0,vB0 OK; P6 reads vB1 OK; P7 reads vA1(P1) OK.
//   P8's vmcnt(6): retires P2,P3,P4,P5
//     => nP1 reads u'A0(P2),u'B0(P3) OK; nP2 reads u'B1(P4) OK;
//        nP3 reads u'A1(P5) OK.  vmcnt never 0 in loop; lead ~5 phases.
// Reads can't hoist across the retiring wait: every wait is asm volatile
// with "memory" clobber. Write-after-read: each stage overwrites a region
// whose last ds_read completed >=1 lgkmcnt(0)+barrier earlier (P2 stages
// over A0 read in P1, etc.) -- safe for async LDS writes.
// Tail: u'/w stages clamp ko=0 (garbage into regions never re-read; counts
// stay uniform). Drain vmcnt(0) after loop.
// ---------------------------------------------------------------------------
#define GL2LDS(g, l) \
    __builtin_amdgcn_global_load_lds( \
        (const __attribute__((address_space(1))) void*)(g), \
        (__attribute__((address_space(3))) void*)(l), 16, 0, 0)

__global__ __launch_bounds__(512, 2) void gemm_bt(
    const unsigned short* __restrict__ A,
    const unsigned short* __restrict__ B,
    float* __restrict__ C)
{
    __shared__ __align__(16) unsigned short As[2][256 * BK];   // 2 x 32 KB
    __shared__ __align__(16) unsigned short Bs[2][256 * BK];   // 2 x 32 KB

    const int tid  = threadIdx.x;
    const int wv   = tid >> 6;         // 0..7
    const int lane = tid & 63;
    const int wm   = wv >> 2;          // 0..1  (M sub-block within each half)
    const int wn   = wv & 3;           // 0..3  (N sub-block within each half)

    const int bid = blockIdx.x;
    const int wg  = (bid & 7) * 32 + (bid >> 3);   // XCD-chunked remap
    const int m0  = (wg >> 2) * 256;               // 64 m-blocks
    const int n0  = (wg & 3) * 256;                // 4 n-blocks

    // staging: per half-tile (128 rows), wave covers 16 rows as 2 loads of
    // 8 rows; lane -> row lane>>3, chunk (lane&7)^(lane>>3) (XOR swizzle).
    const int srow8 = lane >> 3;
    const int schk  = (lane & 7) ^ srow8;
    const char* ag = (const char*)A +
        ((size_t)(m0 + wv * 16 + srow8) * GK + schk * 8) * 2;
    const char* bg = (const char*)B +
        ((size_t)(n0 + wv * 16 + srow8) * GK + schk * 8) * 2;
    const size_t ROW8 = (size_t)8 * GK * 2;     // 8 rows in global bytes
    const size_t HALF = (size_t)128 * GK * 2;   // 128 rows in global bytes

#define STAGE_A(buf, half, ko) do { \
    GL2LDS(ag + (ko) + (half) * HALF,        (char*)As[buf] + ((half) * 128 + wv * 16) * 128); \
    GL2LDS(ag + (ko) + (half) * HALF + ROW8, (char*)As[buf] + ((half) * 128 + wv * 16 + 8) * 128); \
} while (0)
#define STAGE_B(buf, half, ko) do { \
    GL2LDS(bg + (ko) + (half) * HALF,        (char*)Bs[buf] + ((half) * 128 + wv * 16) * 128); \
    GL2LDS(bg + (ko) + (half) * HALF + ROW8, (char*)Bs[buf] + ((half) * 128 + wv * 16 + 8) * 128); \
} while (0)

    // fragment read coordinates -- half-aligned mapping (verified R8)
    const int rr  = lane & 15;
    const int fsw = lane & 7;
    const int cc  = lane >> 4;
#define CHOFF(s) ((((s) * 4 + cc) ^ fsw) * 16)
#define RD_A(dst, Pt, mh) do { \
    _Pragma("unroll") \
    for (int s_ = 0; s_ < 2; ++s_) \
        _Pragma("unroll") \
        for (int i_ = 0; i_ < 4; ++i_) \
            dst[s_][i_] = *(const bf16x8*)((Pt) + \
                ((mh) * 128 + wm * 64 + i_ * 16 + rr) * 128 + CHOFF(s_)); \
} while (0)
#define RD_B(dst, Pt, nh) do { \
    _Pragma("unroll") \
    for (int s_ = 0; s_ < 2; ++s_) \
        _Pragma("unroll") \
        for (int j_ = 0; j_ < 2; ++j_) \
            dst[s_][j_] = *(const bf16x8*)((Pt) + \
                ((nh) * 128 + wn * 32 + j_ * 16 + rr) * 128 + CHOFF(s_)); \
} while (0)

    f32x4 acc[8][4] = {};

#define MFMA16(AF, BF, I0, J0) do { \
    __builtin_amdgcn_s_setprio(1); \
    _Pragma("unroll") \
    for (int s_ = 0; s_ < 2; ++s_) \
        _Pragma("unroll") \
        for (int i_ = 0; i_ < 4; ++i_) \
            _Pragma("unroll") \
            for (int j_ = 0; j_ < 2; ++j_) \
                acc[(I0) + i_][(J0) + j_] = __builtin_amdgcn_mfma_f32_16x16x32_bf16( \
                    AF[s_][i_], BF[s_][j_], acc[(I0) + i_][(J0) + j_], 0, 0, 0); \
    __builtin_amdgcn_s_setprio(0); \
} while (0)

#define BAR      __builtin_amdgcn_s_barrier()
#define LGKM0    asm volatile("s_waitcnt lgkmcnt(0)" ::: "memory")
#define LGKM8    asm volatile("s_waitcnt lgkmcnt(8)" ::: "memory")
#define VM6      asm volatile("s_waitcnt vmcnt(6)" ::: "memory")

    bf16x8 aF[2][4], b0[2][2], b1[2][2];

    // prologue: tile0 fully (A0,B0,B1,A1), tile1 {A0,B0,B1}; vmcnt(6)
    // retires all 8 of tile0, leaves tile1's 6 in flight = steady entry.
    STAGE_A(0, 0, 0);   STAGE_B(0, 0, 0);
    STAGE_B(0, 1, 0);   STAGE_A(0, 1, 0);
    STAGE_A(1, 0, 128); STAGE_B(1, 0, 128); STAGE_B(1, 1, 128);
    VM6;
    BAR;

#pragma unroll 1
    for (int tt = 0; tt < NT / 2; ++tt) {
        const char* A0p = (const char*)As[0];
        const char* B0p = (const char*)Bs[0];
        const char* A1p = (const char*)As[1];
        const char* B1p = (const char*)Bs[1];
        const size_t kv = (size_t)(2 * tt + 1) * 128;                        // tile v
        const size_t k2 = (2 * tt + 2 < NT) ? (size_t)(2 * tt + 2) * 128 : 0; // u'
        const size_t k3 = (2 * tt + 3 < NT) ? (size_t)(2 * tt + 3) * 128 : 0; // w

        // P1: u.Q00 -- read uA0,uB0 (12) | stage vA1
        RD_A(aF, A0p, 0); RD_B(b0, B0p, 0);
        STAGE_A(1, 1, kv);
        LGKM8;
        BAR; LGKM0;
        MFMA16(aF, b0, 0, 0);
        BAR;

        // P2: u.Q01 -- read uB1 (4) | stage u'A0
        RD_B(b1, B0p, 1);
        STAGE_A(0, 0, k2);
        BAR; LGKM0;
        MFMA16(aF, b1, 0, 2);
        BAR;

        // P3: u.Q11 -- read uA1 (8) | stage u'B0
        RD_A(aF, A0p, 1);
        STAGE_B(0, 0, k2);
        BAR; LGKM0;
        MFMA16(aF, b1, 4, 2);
        BAR;

        // P4: u.Q10 -- no reads | stage u'B1 | vmcnt(6)
        STAGE_B(0, 1, k2);
        BAR;
        MFMA16(aF, b0, 4, 0);
        VM6;
        BAR;

        // P5: v.Q00 -- read vA0,vB0 (12) | stage u'A1
        RD_A(aF, A1p, 0); RD_B(b0, B1p, 0);
        STAGE_A(0, 1, k2);
        LGKM8;
        BAR; LGKM0;
        MFMA16(aF, b0, 0, 0);
        BAR;

        // P6: v.Q01 -- read vB1 (4) | stage wA0
        RD_B(b1, B1p, 1);
        STAGE_A(1, 0, k3);
        BAR; LGKM0;
        MFMA16(aF, b1, 0, 2);
        BAR;

        // P7: v.Q11 -- read vA1 (8) | stage wB0
        RD_A(aF, A1p, 1);
        STAGE_B(1, 0, k3);
        BAR; LGKM0;
        MFMA16(aF, b1, 4, 2);
        BAR;

        // P8: v.Q10 -- no reads | stage wB1 | vmcnt(6)
        STAGE_B(1, 1, k3);
        BAR;
        MFMA16(aF, b0, 4, 0);
        VM6;
        BAR;
    }

    // drain tail garbage stages before epilogue
    asm volatile("s_waitcnt vmcnt(0)" ::: "memory");

    // epilogue: per-MFMA C/D layout col = lane&15, row = (lane>>4)*4 + reg;
    // half-aligned block mapping (matches RD_A/RD_B rows)
    const int cn = lane & 15;
    const int rb = (lane >> 4) * 4;
#pragma unroll
    for (int i = 0; i < 8; ++i)
#pragma unroll
        for (int j = 0; j < 4; ++j)
#pragma unroll
            for (int r = 0; r < 4; ++r) {
                const int m = m0 + (i >> 2) * 128 + wm * 64 + (i & 3) * 16 + rb + r;
                const int n = n0 + (j >> 1) * 128 + wn * 32 + (j & 1) * 16 + cn;
                C[(size_t)m * GN + n] = acc[i][j][r];
            }
}

// ---------------------------------------------------------------------------
extern "C" void kernel_launch(void* const* d_in, const int* in_sizes, int n_in,
                              void* d_out, int out_size, void* d_ws, size_t ws_size,
                              hipStream_t stream) {
    const float* x  = (const float*)d_in[0];
    const float* ry = (const float*)d_in[1];
    const float* w1 = (const float*)d_in[2];
    const float* w2 = (const float*)d_in[3];
    float* out = (float*)d_out;

    unsigned short* h   = (unsigned short*)d_ws;                       // 128 MiB
    unsigned short* w2b = (unsigned short*)((char*)d_ws +
                           (size_t)M_TOK * FFN * sizeof(unsigned short));
    // w1cT (160 KB) overlays the w2b region: consumed before conv_w2 writes.
    float* w1cT = (float*)w2b;

    prep_w1<<<dim3(FFN / 256), 256, 0, stream>>>(w1, ry, w1cT);
    compute_h<<<dim3(512, 2), 256, 0, stream>>>(x, w1cT, h);
    conv_w2<<<dim3((EMBED * FFN) / (256 * 8)), 256, 0, stream>>>(w2, w2b);
    gemm_bt<<<dim3(256), 512, 0, stream>>>(h, w2b, out);
}

// Round 10
// 248.875 us; speedup vs baseline: 1.1283x; 1.1255x over previous
//
#include <hip/hip_runtime.h>
#include <stdint.h>

// Problem constants
#define M_TOK   16384        // 8 * 2048 tokens
#define EMBED   1024
#define FFN     4096
#define NQ      10

#define GK 4096
#define GN 1024
#define BK 64
#define NT (GK / BK)         // 64 K-tiles

typedef __attribute__((ext_vector_type(8))) short  bf16x8;
typedef __attribute__((ext_vector_type(4))) float  f32x4;
typedef __attribute__((ext_vector_type(8))) unsigned short u16x8;

static __device__ __forceinline__ unsigned short f2bf(float f) {
    union { float f; unsigned u; } v; v.f = f;
    unsigned r = v.u + 0x7FFF + ((v.u >> 16) & 1);   // round-to-nearest-even
    return (unsigned short)(r >> 16);
}

// ---------------------------------------------------------------------------
// Kernel 1: fused aux -- ONE launch for all pre-GEMM work.
//   blocks [0,1024):    h[t][f] = relu( sum_i cos(x[t][i])cos(ry[i])w1[f][i] )
//                       (R0-style compute_h: measured-best "rest" variant)
//   blocks [1024,3072): w2 fp32 -> bf16 cast (old conv_w2)
// Both outputs are consumed only by gemm_bt (next launch) -> no intra-kernel
// ordering needed. Collapsing 4 launches -> 2 tests the launch/serialization
// -overhead hypothesis for the ~90 us unaccounted gap.
// ---------------------------------------------------------------------------
__global__ __launch_bounds__(256) void fused_aux(
    const float* __restrict__ x,  const float* __restrict__ ry,
    const float* __restrict__ w1, const float* __restrict__ w2,
    unsigned short* __restrict__ h, unsigned short* __restrict__ w2b)
{
    __shared__ float cq[32 * 16];    // 2 KB, stride 16
    __shared__ float cry[NQ];

    const int bid = blockIdx.x;
    const int tid = threadIdx.x;

    if (bid < 1024) {
        // ---- compute_h ----
        const int t0 = (bid >> 1) * 32;
        const int fb = (bid & 1) * 2048 + tid * 8;   // this thread's 8 f's

        if (tid < NQ) cry[tid] = cosf(ry[tid]);
        for (int idx = tid; idx < 32 * NQ; idx += 256) {
            int t = idx / NQ;
            int i = idx - t * NQ;
            cq[t * 16 + i] = cosf(x[(size_t)(t0 + t) * EMBED + i]);
        }
        __syncthreads();

        // premultiply w1 rows by cos(phi): 80 floats in registers
        float wf[8][NQ];
#pragma unroll
        for (int fi = 0; fi < 8; ++fi)
#pragma unroll
            for (int i = 0; i < NQ; ++i)
                wf[fi][i] = w1[(fb + fi) * NQ + i] * cry[i];

        for (int t = 0; t < 32; ++t) {
            const float4 c0 = *(const float4*)&cq[t * 16 + 0];
            const float4 c1 = *(const float4*)&cq[t * 16 + 4];
            const float2 c2 = *(const float2*)&cq[t * 16 + 8];
            u16x8 v;
#pragma unroll
            for (int fi = 0; fi < 8; ++fi) {
                float s = c0.x * wf[fi][0] + c0.y * wf[fi][1] + c0.z * wf[fi][2]
                        + c0.w * wf[fi][3] + c1.x * wf[fi][4] + c1.y * wf[fi][5]
                        + c1.z * wf[fi][6] + c1.w * wf[fi][7] + c2.x * wf[fi][8]
                        + c2.y * wf[fi][9];
                v[fi] = f2bf(fmaxf(s, 0.f));
            }
            *(u16x8*)(h + (size_t)(t0 + t) * FFN + fb) = v;
        }
    } else {
        // ---- conv_w2 ----
        const int idx = ((bid - 1024) * 256 + tid) * 8;
        float4 a = *(const float4*)(w2 + idx);
        float4 b = *(const float4*)(w2 + idx + 4);
        u16x8 v;
        v[0] = f2bf(a.x); v[1] = f2bf(a.y); v[2] = f2bf(a.z); v[3] = f2bf(a.w);
        v[4] = f2bf(b.x); v[5] = f2bf(b.y); v[6] = f2bf(b.z); v[7] = f2bf(b.w);
        *(u16x8*)(w2b + idx) = v;
    }
}

// ---------------------------------------------------------------------------
// Kernel 2: C[M][N] = A[M][K] * B[N][K]^T   (bf16 in, fp32 out)
// R6 version VERBATIM (best measured: 126.3 us, MfmaUtil 46%).
// Register-pipelined 4-phase schedule: every MFMA cluster consumes fragments
// ds_read >= 1 phase EARLIER; compiler's dependency-driven counted lgkmcnt
// implements the lookahead. 2 barriers/tile. XOR chunk swizzle, 0 conflicts.
// ---------------------------------------------------------------------------
#define GL2LDS(g, l) \
    __builtin_amdgcn_global_load_lds( \
        (const __attribute__((address_space(1))) void*)(g), \
        (__attribute__((address_space(3))) void*)(l), 16, 0, 0)

__global__ __launch_bounds__(512, 2) void gemm_bt(
    const unsigned short* __restrict__ A,
    const unsigned short* __restrict__ B,
    float* __restrict__ C)
{
    __shared__ __align__(16) unsigned short As[2][256 * BK];   // 2 x 32 KB
    __shared__ __align__(16) unsigned short Bs[2][256 * BK];   // 2 x 32 KB

    const int tid  = threadIdx.x;
    const int wv   = tid >> 6;         // 0..7
    const int lane = tid & 63;
    const int wm   = wv >> 2;          // 0..1  (M half)
    const int wn   = wv & 3;           // 0..3  (N quarter)

    const int bid = blockIdx.x;
    const int wg  = (bid & 7) * 32 + (bid >> 3);   // XCD-chunked remap
    const int m0  = (wg >> 2) * 256;               // 64 m-blocks
    const int n0  = (wg & 3) * 256;                // 4 n-blocks

    // staging: per half-tile (128 rows), wave covers 16 rows as 2 loads of
    // 8 rows; lane -> row lane>>3, chunk (lane&7)^(lane>>3) (XOR swizzle).
    const int srow8 = lane >> 3;
    const int schk  = (lane & 7) ^ srow8;
    const char* ag = (const char*)A +
        ((size_t)(m0 + wv * 16 + srow8) * GK + schk * 8) * 2;
    const char* bg = (const char*)B +
        ((size_t)(n0 + wv * 16 + srow8) * GK + schk * 8) * 2;
    const size_t ROW8 = (size_t)8 * GK * 2;     // 8 rows in global bytes
    const size_t HALF = (size_t)128 * GK * 2;   // 128 rows in global bytes

#define STAGE_A(buf, half, ko) do { \
    GL2LDS(ag + (ko) + (half) * HALF,        (char*)As[buf] + ((half) * 128 + wv * 16) * 128); \
    GL2LDS(ag + (ko) + (half) * HALF + ROW8, (char*)As[buf] + ((half) * 128 + wv * 16 + 8) * 128); \
} while (0)
#define STAGE_B(buf, half, ko) do { \
    GL2LDS(bg + (ko) + (half) * HALF,        (char*)Bs[buf] + ((half) * 128 + wv * 16) * 128); \
    GL2LDS(bg + (ko) + (half) * HALF + ROW8, (char*)Bs[buf] + ((half) * 128 + wv * 16 + 8) * 128); \
} while (0)
#define STAGE_ALL(buf, ko) do { \
    STAGE_A(buf, 0, ko); STAGE_A(buf, 1, ko); \
    STAGE_B(buf, 0, ko); STAGE_B(buf, 1, ko); \
} while (0)

    // fragment read coordinates (verified layout)
    const int rr  = lane & 15;
    const int fsw = lane & 7;
    const int cc  = lane >> 4;
#define CHOFF(s) ((((s) * 4 + cc) ^ fsw) * 16)
#define RD_A(dst, Pt, mh) do { \
    _Pragma("unroll") \
    for (int s_ = 0; s_ < 2; ++s_) \
        _Pragma("unroll") \
        for (int i_ = 0; i_ < 4; ++i_) \
            dst[s_][i_] = *(const bf16x8*)((Pt) + \
                (wm * 128 + (mh) * 64 + i_ * 16 + rr) * 128 + CHOFF(s_)); \
} while (0)
#define RD_B(dst, Pt, nh) do { \
    _Pragma("unroll") \
    for (int s_ = 0; s_ < 2; ++s_) \
        _Pragma("unroll") \
        for (int j_ = 0; j_ < 2; ++j_) \
            dst[s_][j_] = *(const bf16x8*)((Pt) + \
                (wn * 64 + (nh) * 32 + j_ * 16 + rr) * 128 + CHOFF(s_)); \
} while (0)

    f32x4 acc[8][4] = {};

#define MFMA16(AF, BF, I0, J0) do { \
    __builtin_amdgcn_s_setprio(1); \
    _Pragma("unroll") \
    for (int s_ = 0; s_ < 2; ++s_) \
        _Pragma("unroll") \
        for (int i_ = 0; i_ < 4; ++i_) \
            _Pragma("unroll") \
            for (int j_ = 0; j_ < 2; ++j_) \
                acc[(I0) + i_][(J0) + j_] = __builtin_amdgcn_mfma_f32_16x16x32_bf16( \
                    AF[s_][i_], BF[s_][j_], acc[(I0) + i_][(J0) + j_], 0, 0, 0); \
    __builtin_amdgcn_s_setprio(0); \
} while (0)

    bf16x8 aA[2][4], aB[2][4], bP[2][2], bQ[2][2];

    // prologue: stage tiles 0 and 1; wait for tile 0 only (counted vmcnt);
    // preload tile 0's A0,B0 fragments.
    STAGE_ALL(0, 0);
    STAGE_ALL(1, 128);
    asm volatile("s_waitcnt vmcnt(8)" ::: "memory");
    __builtin_amdgcn_s_barrier();
    RD_A(aA, (const char*)As[0], 0);
    RD_B(bP, (const char*)Bs[0], 0);

    // TILE body: BPm holds current B0, BQm gets B1 then next tile's B0.
#define TILE(T, cur, nxt, BPm, BQm, doRead, doStage, ko2) do { \
    const char* At = (const char*)As[cur]; \
    const char* Bt = (const char*)Bs[cur]; \
    /* P1 */ \
    RD_B(BQm, Bt, 1); \
    MFMA16(aA, BPm, 0, 0); \
    /* P2 */ \
    RD_A(aB, At, 1); \
    MFMA16(aA, BQm, 0, 2); \
    /* P3 */ \
    MFMA16(aB, BQm, 4, 2); \
    asm volatile("s_waitcnt vmcnt(0)" ::: "memory"); \
    __builtin_amdgcn_s_barrier(); \
    __builtin_amdgcn_sched_barrier(0); \
    /* P4 */ \
    if (doRead) { \
        const char* An = (const char*)As[nxt]; \
        const char* Bn = (const char*)Bs[nxt]; \
        RD_A(aA, An, 0); \
        RD_B(BQm, Bn, 0); \
    } \
    if (doStage) STAGE_ALL(cur, ko2); \
    MFMA16(aB, BPm, 4, 0); \
} while (0)

#pragma unroll 1
    for (int tt = 0; tt < NT / 2; ++tt) {
        const bool nl = (tt < NT / 2 - 1);     // not last iteration
        // tile 2tt   (cur=0): reads of T+1 always real; stage T+2 if nl
        TILE(2 * tt, 0, 1, bP, bQ, true, nl, (size_t)(2 * tt + 2) * 128);
        // tile 2tt+1 (cur=1): reads+stage real if nl
        TILE(2 * tt + 1, 1, 0, bQ, bP, nl, nl, (size_t)(2 * tt + 3) * 128);
    }

    // epilogue: C/D layout col = lane&15, row = (lane>>4)*4 + reg
    const int cn = lane & 15;
    const int rb = (lane >> 4) * 4;
#pragma unroll
    for (int i = 0; i < 8; ++i)
#pragma unroll
        for (int j = 0; j < 4; ++j)
#pragma unroll
            for (int r = 0; r < 4; ++r) {
                const int m = m0 + wm * 128 + i * 16 + rb + r;
                const int n = n0 + wn * 64 + j * 16 + cn;
                C[(size_t)m * GN + n] = acc[i][j][r];
            }
}

// ---------------------------------------------------------------------------
extern "C" void kernel_launch(void* const* d_in, const int* in_sizes, int n_in,
                              void* d_out, int out_size, void* d_ws, size_t ws_size,
                              hipStream_t stream) {
    const float* x  = (const float*)d_in[0];
    const float* ry = (const float*)d_in[1];
    const float* w1 = (const float*)d_in[2];
    const float* w2 = (const float*)d_in[3];
    float* out = (float*)d_out;

    unsigned short* h   = (unsigned short*)d_ws;                       // 128 MiB
    unsigned short* w2b = (unsigned short*)((char*)d_ws +
                           (size_t)M_TOK * FFN * sizeof(unsigned short));

    fused_aux<<<dim3(1024 + 2048), 256, 0, stream>>>(x, ry, w1, w2, h, w2b);
    gemm_bt<<<dim3(256), 512, 0, stream>>>(h, w2b, out);
}